// Round 11
// baseline (125.316 us; speedup 1.0000x reference)
//
#include <hip/hip_runtime.h>
#include <hip/hip_bf16.h>

#define CIN 32
#define OCH 64
#define HH  256
#define WW  256
#define HW  (HH * WW)
#define BH  8                 // output rows per block
#define ROWB (258 * 64)       // 16512 B per LDS row-slot
#define XROWB (WW * CIN * 2)  // 16384 B per xt row

typedef __bf16 bf16x8 __attribute__((ext_vector_type(8)));
typedef float  f32x4  __attribute__((ext_vector_type(4)));
typedef float  f32x16 __attribute__((ext_vector_type(16)));

typedef __attribute__((address_space(3))) unsigned int lds_u32;
typedef const __attribute__((address_space(1))) unsigned int glb_u32;

__device__ inline void gload_lds16(const void* g, void* l) {
    __builtin_amdgcn_global_load_lds((glb_u32*)g, (lds_u32*)l, 16, 0, 0);
}

// ---------------------------------------------------------------------------
// Pass 1: x[b][c][h][w] f32 -> xt[b][h] rows of 256 w-entries (64 B each):
// chunk for channels sc*8..+7 stored at position sc ^ ((w>>1)&3)  (the
// bank-conflict-free swizzle the conv's ds_read expects; r2-proven layout).
__global__ __launch_bounds__(256) void xprep_kernel(const float* __restrict__ x,
                                                    __bf16* __restrict__ xt) {
    const int h = blockIdx.x, b = blockIdx.y;
    const int tid = threadIdx.x;
    const int cg = tid >> 6;          // channel-group: channels cg*8..+7
    const int wl = tid & 63;

    __shared__ __bf16 ls[WW][CIN];    // 16 KiB, one swizzled output row

    const float* xb = x + ((size_t)b * CIN + cg * 8) * HW + (size_t)h * WW;
#pragma unroll
    for (int wh = 0; wh < 2; ++wh) {
        const int w0 = wh * 128 + wl * 2;
        float2 v[8];
#pragma unroll
        for (int j = 0; j < 8; ++j)
            v[j] = *(const float2*)(xb + (size_t)j * HW + w0);
#pragma unroll
        for (int p = 0; p < 2; ++p) {
            const int w = w0 + p;
            bf16x8 pk;
#pragma unroll
            for (int j = 0; j < 8; ++j) pk[j] = (__bf16)(p ? v[j].y : v[j].x);
            const int sp = cg ^ ((w >> 1) & 3);
            *(bf16x8*)((char*)&ls[0][0] + w * 64 + sp * 16) = pk;
        }
    }
    __syncthreads();

    f32x4* dst = (f32x4*)((char*)xt + ((size_t)b * HH + h) * XROWB);
    const f32x4* src = (const f32x4*)&ls[0][0];
#pragma unroll
    for (int q = 0; q < 4; ++q)
        dst[q * 256 + tid] = src[q * 256 + tid];
}

// ---------------------------------------------------------------------------
// Pass 2: fused sliding-window conv. Staging = 4 global_load_lds(16B)/wave
// from the L3-resident xt (linear copy; swizzle lives in xt's layout).
// Compute/store = r9/r10 structure (32x32x16 swapped-operand MFMA, f32x4
// stores). Barrier uses counted drain: vmcnt(16) retires the 4 staging loads,
// leaves the 16 output stores in flight (in-order vmcnt).
__global__ __launch_bounds__(256, 1) void conv_main_kernel(
        const __bf16* __restrict__ xt, const float* __restrict__ wgt,
        const float* __restrict__ bias, float* __restrict__ out) {
    // chunked XCD swizzle: 512 blocks, 64 consecutive nids per XCD.
    const int bid = blockIdx.x;
    const int nid = (bid & 7) * 64 + (bid >> 3);
    const int b   = nid >> 5;                    // 0..15
    const int h0  = (nid & 31) * BH;             // 0..248
    const int tid = threadIdx.x;
    const int l   = tid & 63, wid = tid >> 6;
    const int lw  = l & 31,  hi  = l >> 5;
    const int og  = wid & 1;                     // o-half
    const int wf  = wid >> 1;                    // w-half

    __shared__ char lds4[4][ROWB];               // 66,048 B ring of 4 row-slots
    char* lds = &lds4[0][0];
    const char* xtb = (const char*)xt + (size_t)b * HH * XROWB;

    // zero the w-pad entries (wp=0 and wp=257) of all 4 slots; staging only
    // touches wp=1..256 so pads stay zero across ring reuse.
    if (tid < 32) {
        const int s = tid >> 3, k = tid & 7;
        const int wp = (k < 4) ? 0 : 257;
        *(f32x4*)(lds + s * ROWB + wp * 64 + (k & 3) * 16) = (f32x4){0, 0, 0, 0};
    }

    // ---- weights: af[t][ks][j] = wgt[og*32+lw][ c = ks*16 + hi*8 + j, tap t ]
    bf16x8 af[9][2];
    {
        const float* wrow = wgt + (size_t)(og * 32 + lw) * 288 + hi * 72;
#pragma unroll
        for (int ks = 0; ks < 2; ++ks)
#pragma unroll
            for (int t = 0; t < 9; ++t)
#pragma unroll
                for (int j = 0; j < 8; ++j)
                    af[t][ks][j] = (__bf16)wrow[ks * 144 + j * 9 + t];
    }
    const float bsc = bias[og * 32 + lw];        // transposed D: one o per lane

    // ---- prologue staging: rows h0-1, h0, h0+1 (linear 16 KB copies)
#pragma unroll
    for (int r = 0; r < 3; ++r) {
        const int row = h0 - 1 + r;
        char* slot = lds + ((row + 1) & 3) * ROWB + 64;   // wp=1 base
        if (row >= 0) {                                   // row<HH always here
            const char* src = xtb + (size_t)row * XROWB;
#pragma unroll
            for (int k = 0; k < 4; ++k) {
                const int o4 = (wid * 4 + k) * 1024 + l * 16;
                gload_lds16(src + o4, slot + o4);
            }
        } else {
#pragma unroll
            for (int k = 0; k < 4; ++k)
                *(f32x4*)(slot + (wid * 4 + k) * 1024 + l * 16) = (f32x4){0, 0, 0, 0};
        }
    }

    // ---- B-read lane offsets (r8-r10; conflict-free; matches xt swizzle)
    int off6[3][2];
#pragma unroll
    for (int kw = 0; kw < 3; ++kw) {
        const int e = lw + kw;
        const int m = (e == 0) ? 3 : (((e - 1) >> 1) & 3);
#pragma unroll
        for (int ks = 0; ks < 2; ++ks)
            off6[kw][ks] = e * 64 + (((ks * 2 + hi) ^ m) << 4);
    }
    const int halfoff = wf * (128 * 64);

    __syncthreads();   // prologue: full drain (compiler emits vmcnt(0))

    for (int i = 0; i < BH; ++i) {
        const int h = h0 + i;

        // (1) stage row h+2 -> slot (h+3)&3 (free slot this iter; its last
        //     readers finished before the previous barrier)
        if (i < BH - 1) {
            const int rs = h + 2;
            char* slot = lds + ((rs + 1) & 3) * ROWB + 64;
            if (rs < HH) {
                const char* src = xtb + (size_t)rs * XROWB;
#pragma unroll
                for (int k = 0; k < 4; ++k) {
                    const int o4 = (wid * 4 + k) * 1024 + l * 16;
                    gload_lds16(src + o4, slot + o4);
                }
            } else {
#pragma unroll
                for (int k = 0; k < 4; ++k)
                    *(f32x4*)(slot + (wid * 4 + k) * 1024 + l * 16) =
                        (f32x4){0, 0, 0, 0};
            }
        }
        __builtin_amdgcn_sched_barrier(0);   // keep staging issued early

        // (2) MFMA (swapped operands -> transposed D): input rows h-1..h+1
        const char* s0 = lds + ((h    ) & 3) * ROWB + halfoff;
        const char* s1 = lds + ((h + 1) & 3) * ROWB + halfoff;
        const char* s2 = lds + ((h + 2) & 3) * ROWB + halfoff;
        f32x16 acc[4];
#pragma unroll
        for (int t = 0; t < 4; ++t)
#pragma unroll
            for (int r = 0; r < 16; ++r) acc[t][r] = bsc;
#pragma unroll
        for (int t = 0; t < 4; ++t) {
#pragma unroll
            for (int kh = 0; kh < 3; ++kh) {
                const char* s = (kh == 0) ? s0 : (kh == 1) ? s1 : s2;
#pragma unroll
                for (int ks = 0; ks < 2; ++ks)
#pragma unroll
                    for (int kw = 0; kw < 3; ++kw) {
                        bf16x8 bf = *(const bf16x8*)(s + t * 2048 + off6[kw][ks]);
                        acc[t] = __builtin_amdgcn_mfma_f32_32x32x16_bf16(
                            bf, af[kh * 3 + kw][ks], acc[t], 0, 0, 0);
                    }
            }
        }

        // (3) store row h: lane owns o = og*32+lw; regs 4q..4q+3 = 4 consec w
        float* outb = out + ((size_t)b * OCH + og * 32 + lw) * HW +
                      (size_t)h * WW + wf * 128 + 4 * hi;
#pragma unroll
        for (int t = 0; t < 4; ++t)
#pragma unroll
            for (int q = 0; q < 4; ++q) {
                f32x4 val = { acc[t][4 * q], acc[t][4 * q + 1],
                              acc[t][4 * q + 2], acc[t][4 * q + 3] };
                *(f32x4*)(outb + t * 32 + 8 * q) = val;
            }

        // (4) counted-drain barrier: retires the 4 staging gloads (older),
        //     leaves the 16 output stores (newest) in flight; lgkmcnt(0)
        //     covers zero-fill ds_writes and in-flight ds_reads.
        if (i < BH - 1) {
            __builtin_amdgcn_sched_barrier(0);
            asm volatile("s_waitcnt vmcnt(16) lgkmcnt(0)" ::: "memory");
            __builtin_amdgcn_s_barrier();
            __builtin_amdgcn_sched_barrier(0);
        }
    }
}

// ---------------------------------------------------------------------------
// Fallback (r10 single-kernel, proven 110 us) if workspace < 64 MiB.
__global__ __launch_bounds__(256, 1) void conv_fallback_kernel(
        const float* __restrict__ x, const float* __restrict__ wgt,
        const float* __restrict__ bias, float* __restrict__ out) {
    const int bid = blockIdx.x;
    const int nid = (bid & 7) * 64 + (bid >> 3);
    const int b   = nid >> 5;
    const int h0  = (nid & 31) * BH;
    const int tid = threadIdx.x;
    const int l   = tid & 63, wid = tid >> 6;
    const int lw  = l & 31,  hi  = l >> 5;
    const int og  = wid & 1;
    const int wf  = wid >> 1;

    __shared__ __bf16 xs[4][258][CIN];
    char* lds = (char*)&xs[0][0][0];
    const float* xb = x + (size_t)b * CIN * HW;

    if (tid < 32) {
        const int s = tid >> 3, k = tid & 7;
        const int wp = (k < 4) ? 0 : 257;
        *(f32x4*)(lds + s * ROWB + wp * 64 + (k & 3) * 16) = (f32x4){0, 0, 0, 0};
    }
    bf16x8 af[9][2];
    {
        const float* wrow = wgt + (size_t)(og * 32 + lw) * 288 + hi * 72;
#pragma unroll
        for (int ks = 0; ks < 2; ++ks)
#pragma unroll
            for (int t = 0; t < 9; ++t)
#pragma unroll
                for (int j = 0; j < 8; ++j)
                    af[t][ks][j] = (__bf16)wrow[ks * 144 + j * 9 + t];
    }
    const float bsc = bias[og * 32 + lw];

    auto stage = [&](int row) {
        char* slot = lds + ((row + 1) & 3) * ROWB;
        if (row >= 0 && row < HH) {
            const float* rp = xb + (size_t)row * WW;
            f32x4 v[8];
#pragma unroll
            for (int j = 0; j < 8; ++j)
                v[j] = *(const f32x4*)(rp + (size_t)(wid * 8 + j) * HW + 4 * l);
#pragma unroll
            for (int p = 0; p < 4; ++p) {
                const int w = 4 * l + p;
                bf16x8 pk;
#pragma unroll
                for (int j = 0; j < 8; ++j) pk[j] = (__bf16)v[j][p];
                *(bf16x8*)(slot + (w + 1) * 64 + ((wid ^ ((w >> 1) & 3)) << 4)) = pk;
            }
        } else {
#pragma unroll
            for (int p = 0; p < 4; ++p) {
                const int w = 4 * l + p;
                *(f32x4*)(slot + (w + 1) * 64 + ((wid ^ ((w >> 1) & 3)) << 4)) =
                    (f32x4){0, 0, 0, 0};
            }
        }
    };
    stage(h0 - 1); stage(h0); stage(h0 + 1);

    int off6[3][2];
#pragma unroll
    for (int kw = 0; kw < 3; ++kw) {
        const int e = lw + kw;
        const int m = (e == 0) ? 3 : (((e - 1) >> 1) & 3);
#pragma unroll
        for (int ks = 0; ks < 2; ++ks)
            off6[kw][ks] = e * 64 + (((ks * 2 + hi) ^ m) << 4);
    }
    const int halfoff = wf * (128 * 64);

    __syncthreads();

    for (int i = 0; i < BH; ++i) {
        const int h  = h0 + i;
        const int nr = h + 2;
        const bool havenext = (i < BH - 1);
        const bool rok2 = havenext && (nr < HH);

        f32x4 v[8];
#pragma unroll
        for (int j = 0; j < 8; ++j) v[j] = (f32x4){0, 0, 0, 0};
        if (rok2) {
            const float* rp = xb + (size_t)nr * WW;
#pragma unroll
            for (int j = 0; j < 8; ++j)
                v[j] = *(const f32x4*)(rp + (size_t)(wid * 8 + j) * HW + 4 * l);
        }

        const char* s0 = lds + ((h    ) & 3) * ROWB + halfoff;
        const char* s1 = lds + ((h + 1) & 3) * ROWB + halfoff;
        const char* s2 = lds + ((h + 2) & 3) * ROWB + halfoff;
        f32x16 acc[4];
#pragma unroll
        for (int t = 0; t < 4; ++t)
#pragma unroll
            for (int r = 0; r < 16; ++r) acc[t][r] = bsc;
#pragma unroll
        for (int t = 0; t < 4; ++t) {
#pragma unroll
            for (int kh = 0; kh < 3; ++kh) {
                const char* s = (kh == 0) ? s0 : (kh == 1) ? s1 : s2;
#pragma unroll
                for (int ks = 0; ks < 2; ++ks)
#pragma unroll
                    for (int kw = 0; kw < 3; ++kw) {
                        bf16x8 bf = *(const bf16x8*)(s + t * 2048 + off6[kw][ks]);
                        acc[t] = __builtin_amdgcn_mfma_f32_32x32x16_bf16(
                            bf, af[kh * 3 + kw][ks], acc[t], 0, 0, 0);
                    }
            }
        }

        float* outb = out + ((size_t)b * OCH + og * 32 + lw) * HW +
                      (size_t)h * WW + wf * 128 + 4 * hi;
#pragma unroll
        for (int t = 0; t < 4; ++t)
#pragma unroll
            for (int q = 0; q < 4; ++q) {
                f32x4 val = { acc[t][4 * q], acc[t][4 * q + 1],
                              acc[t][4 * q + 2], acc[t][4 * q + 3] };
                *(f32x4*)(outb + t * 32 + 8 * q) = val;
            }

        if (havenext) {
            char* slot = lds + ((nr + 1) & 3) * ROWB;
#pragma unroll
            for (int p = 0; p < 4; ++p) {
                const int w = 4 * l + p;
                bf16x8 pk;
#pragma unroll
                for (int j = 0; j < 8; ++j) pk[j] = (__bf16)v[j][p];
                *(bf16x8*)(slot + (w + 1) * 64 + ((wid ^ ((w >> 1) & 3)) << 4)) = pk;
            }
            __builtin_amdgcn_sched_barrier(0);
            asm volatile("s_waitcnt lgkmcnt(0)" ::: "memory");
            __builtin_amdgcn_s_barrier();
            __builtin_amdgcn_sched_barrier(0);
        }
    }
}

// ---------------------------------------------------------------------------
extern "C" void kernel_launch(void* const* d_in, const int* in_sizes, int n_in,
                              void* d_out, int out_size, void* d_ws, size_t ws_size,
                              hipStream_t stream) {
    const float* x    = (const float*)d_in[0];
    const float* w    = (const float*)d_in[1];
    const float* bias = (const float*)d_in[2];
    float* out = (float*)d_out;

    const size_t XT_BYTES = (size_t)16 * HH * XROWB;   // 64 MiB
    if (ws_size >= XT_BYTES) {
        __bf16* xt = (__bf16*)d_ws;
        hipLaunchKernelGGL(xprep_kernel, dim3(HH, 16), dim3(256), 0, stream, x, xt);
        hipLaunchKernelGGL(conv_main_kernel, dim3(512), dim3(256), 0, stream,
                           xt, w, bias, out);
    } else {
        hipLaunchKernelGGL(conv_fallback_kernel, dim3(512), dim3(256), 0, stream,
                           x, w, bias, out);
    }
}